// Round 1
// baseline (565.560 us; speedup 1.0000x reference)
//
#include <hip/hip_runtime.h>

#define E_NUM 8
#define FFN_DIM 8192
#define D_DIM 2048
#define T_DIM 4096

using bf16x8 = __attribute__((ext_vector_type(8))) short;
using f32x4  = __attribute__((ext_vector_type(4))) float;
using u16x8  = __attribute__((ext_vector_type(8))) unsigned short;

__device__ __forceinline__ unsigned short f2bf(float f) {
  union { float f; unsigned int u; } v; v.f = f;
  unsigned int u = v.u;
  unsigned int r = (u + 0x7FFFu + ((u >> 16) & 1u)) >> 16;
  return (unsigned short)r;
}

__device__ __forceinline__ void gload16(const unsigned short* g, unsigned short* l) {
  __builtin_amdgcn_global_load_lds(
      (const __attribute__((address_space(1))) void*)g,
      (__attribute__((address_space(3))) void*)l, 16, 0, 0);
}

// ---------- prep: fp32 -> bf16 convert (optionally slab-offset by *eidx) ----------
__global__ void convert_kernel(const float* __restrict__ src_base,
                               const int* __restrict__ eidx, long slab,
                               unsigned short* __restrict__ dst, long n) {
  const float* src = src_base + (long)(*eidx) * slab;
  long stride = (long)gridDim.x * blockDim.x;
  for (long i = (long)blockIdx.x * blockDim.x + threadIdx.x; i * 8 < n; i += stride) {
    long e = i * 8;
    const float4* p = (const float4*)(src + e);
    float4 f0 = p[0], f1 = p[1];
    u16x8 o;
    o[0] = f2bf(f0.x); o[1] = f2bf(f0.y); o[2] = f2bf(f0.z); o[3] = f2bf(f0.w);
    o[4] = f2bf(f1.x); o[5] = f2bf(f1.y); o[6] = f2bf(f1.z); o[7] = f2bf(f1.w);
    *(u16x8*)(dst + e) = o;
  }
}

// ---------- prep: transpose w2 slab (FFN,D) fp32 -> (D,FFN) bf16 ----------
__global__ void transpose_kernel(const float* __restrict__ w2,
                                 const int* __restrict__ eidx,
                                 unsigned short* __restrict__ dst) {
  __shared__ unsigned short tile[32][33];
  const float* src = w2 + (long)(*eidx) * (long)FFN_DIM * D_DIM;
  int d0 = blockIdx.x << 5;           // D/32 = 64
  int f0 = blockIdx.y << 5;           // FFN/32 = 256
  int tx = threadIdx.x & 31, ty = threadIdx.x >> 5;  // 32 x 8
#pragma unroll
  for (int i = 0; i < 4; ++i) {
    int f = ty + i * 8;
    tile[f][tx] = f2bf(src[(long)(f0 + f) * D_DIM + d0 + tx]);
  }
  __syncthreads();
#pragma unroll
  for (int i = 0; i < 4; ++i) {
    int d = ty + i * 8;
    dst[(long)(d0 + d) * FFN_DIM + f0 + tx] = tile[tx][d];
  }
}

// ---------- GEMM1 fused: h = silu(X*W1^T) .* (X*V1^T), bf16 out ----------
// tile 128(m) x 64(n), BK=32, 4 waves in 2x2, each wave 64m x 32n
__global__ __launch_bounds__(256) void gemm1_silu(
    const unsigned short* __restrict__ Xb,    // (4096,2048)
    const unsigned short* __restrict__ W1b,   // (8192,2048)
    const unsigned short* __restrict__ V1b,   // (8192,2048)
    unsigned short* __restrict__ Hb) {        // (4096,8192)
  __shared__ __align__(16) unsigned short sA[128 * 32];
  __shared__ __align__(16) unsigned short sB1[64 * 32];
  __shared__ __align__(16) unsigned short sB2[64 * 32];

  const int tid = threadIdx.x;
  const int w = tid >> 6, l = tid & 63;
  const int m0 = blockIdx.y << 7;   // 32 m-blocks
  const int n0 = blockIdx.x << 6;   // 128 n-blocks
  const int wm = w >> 1, wn = w & 1;
  const int kq = l >> 4, lr = l & 15;

  f32x4 z = {0.f, 0.f, 0.f, 0.f};
  f32x4 acc1[4][2], acc2[4][2];
#pragma unroll
  for (int m = 0; m < 4; ++m)
#pragma unroll
    for (int n = 0; n < 2; ++n) { acc1[m][n] = z; acc2[m][n] = z; }

  // staging geometry: chunk c covers rows [c*16, c*16+16), lane l -> row c*16+l/4, col (l&3)*8
  const int colg = (l & 3) * 8;
  const int rsub = l >> 2;
  const unsigned short* gA0 = Xb + (long)(m0 + (w * 2 + 0) * 16 + rsub) * D_DIM + colg;
  const unsigned short* gA1 = Xb + (long)(m0 + (w * 2 + 1) * 16 + rsub) * D_DIM + colg;
  const unsigned short* gB1 = W1b + (long)(n0 + w * 16 + rsub) * D_DIM + colg;
  const unsigned short* gB2 = V1b + (long)(n0 + w * 16 + rsub) * D_DIM + colg;
  unsigned short* lA0 = sA + (w * 2 + 0) * 512;
  unsigned short* lA1 = sA + (w * 2 + 1) * 512;
  unsigned short* lB1 = sB1 + w * 512;
  unsigned short* lB2 = sB2 + w * 512;

  for (int k0 = 0; k0 < D_DIM; k0 += 32) {
    if (k0) __syncthreads();
    gload16(gA0 + k0, lA0);
    gload16(gA1 + k0, lA1);
    gload16(gB1 + k0, lB1);
    gload16(gB2 + k0, lB2);
    __syncthreads();

    const bf16x8* pA = (const bf16x8*)sA;
    const bf16x8* pB1 = (const bf16x8*)sB1;
    const bf16x8* pB2 = (const bf16x8*)sB2;
    bf16x8 a[4], b1[2], b2[2];
#pragma unroll
    for (int m = 0; m < 4; ++m) a[m] = pA[(wm * 64 + m * 16 + lr) * 4 + kq];
#pragma unroll
    for (int n = 0; n < 2; ++n) {
      b1[n] = pB1[(wn * 32 + n * 16 + lr) * 4 + kq];
      b2[n] = pB2[(wn * 32 + n * 16 + lr) * 4 + kq];
    }
#pragma unroll
    for (int m = 0; m < 4; ++m)
#pragma unroll
      for (int n = 0; n < 2; ++n) {
        acc1[m][n] = __builtin_amdgcn_mfma_f32_16x16x32_bf16(a[m], b1[n], acc1[m][n], 0, 0, 0);
        acc2[m][n] = __builtin_amdgcn_mfma_f32_16x16x32_bf16(a[m], b2[n], acc2[m][n], 0, 0, 0);
      }
  }

  // epilogue: h = silu(x1)*x2, bf16
#pragma unroll
  for (int m = 0; m < 4; ++m)
#pragma unroll
    for (int n = 0; n < 2; ++n)
#pragma unroll
      for (int r = 0; r < 4; ++r) {
        int row = m0 + wm * 64 + m * 16 + kq * 4 + r;
        int col = n0 + wn * 32 + n * 16 + lr;
        float x1 = acc1[m][n][r], x2 = acc2[m][n][r];
        float hv = x1 / (1.f + __expf(-x1)) * x2;
        Hb[(long)row * FFN_DIM + col] = f2bf(hv);
      }
}

// ---------- GEMM2: out = h @ w2  (A=(4096,8192) bf16, Bt=(2048,8192) bf16, out fp32) ----------
// tile 128x128, BK=32, 4 waves 2x2, each wave 64x64
__global__ __launch_bounds__(256) void gemm2(
    const unsigned short* __restrict__ Hb,
    const unsigned short* __restrict__ W2T,
    float* __restrict__ out) {
  __shared__ __align__(16) unsigned short sA[128 * 32];
  __shared__ __align__(16) unsigned short sB[128 * 32];

  const int tid = threadIdx.x;
  const int w = tid >> 6, l = tid & 63;
  const int m0 = blockIdx.y << 7;   // 32
  const int n0 = blockIdx.x << 7;   // 16
  const int wm = w >> 1, wn = w & 1;
  const int kq = l >> 4, lr = l & 15;

  f32x4 z = {0.f, 0.f, 0.f, 0.f};
  f32x4 acc[4][4];
#pragma unroll
  for (int m = 0; m < 4; ++m)
#pragma unroll
    for (int n = 0; n < 4; ++n) acc[m][n] = z;

  const int colg = (l & 3) * 8;
  const int rsub = l >> 2;
  const unsigned short* gA0 = Hb + (long)(m0 + (w * 2 + 0) * 16 + rsub) * FFN_DIM + colg;
  const unsigned short* gA1 = Hb + (long)(m0 + (w * 2 + 1) * 16 + rsub) * FFN_DIM + colg;
  const unsigned short* gB0 = W2T + (long)(n0 + (w * 2 + 0) * 16 + rsub) * FFN_DIM + colg;
  const unsigned short* gB1 = W2T + (long)(n0 + (w * 2 + 1) * 16 + rsub) * FFN_DIM + colg;
  unsigned short* lA0 = sA + (w * 2 + 0) * 512;
  unsigned short* lA1 = sA + (w * 2 + 1) * 512;
  unsigned short* lB0 = sB + (w * 2 + 0) * 512;
  unsigned short* lB1 = sB + (w * 2 + 1) * 512;

  for (int k0 = 0; k0 < FFN_DIM; k0 += 32) {
    if (k0) __syncthreads();
    gload16(gA0 + k0, lA0);
    gload16(gA1 + k0, lA1);
    gload16(gB0 + k0, lB0);
    gload16(gB1 + k0, lB1);
    __syncthreads();

    const bf16x8* pA = (const bf16x8*)sA;
    const bf16x8* pB = (const bf16x8*)sB;
    bf16x8 a[4], b[4];
#pragma unroll
    for (int m = 0; m < 4; ++m) a[m] = pA[(wm * 64 + m * 16 + lr) * 4 + kq];
#pragma unroll
    for (int n = 0; n < 4; ++n) b[n] = pB[(wn * 64 + n * 16 + lr) * 4 + kq];
#pragma unroll
    for (int m = 0; m < 4; ++m)
#pragma unroll
      for (int n = 0; n < 4; ++n)
        acc[m][n] = __builtin_amdgcn_mfma_f32_16x16x32_bf16(a[m], b[n], acc[m][n], 0, 0, 0);
  }

#pragma unroll
  for (int m = 0; m < 4; ++m)
#pragma unroll
    for (int n = 0; n < 4; ++n)
#pragma unroll
      for (int r = 0; r < 4; ++r) {
        int row = m0 + wm * 64 + m * 16 + kq * 4 + r;
        int col = n0 + wn * 64 + n * 16 + lr;
        out[(long)row * D_DIM + col] = acc[m][n][r];
      }
}

extern "C" void kernel_launch(void* const* d_in, const int* in_sizes, int n_in,
                              void* d_out, int out_size, void* d_ws, size_t ws_size,
                              hipStream_t stream) {
  const float* x  = (const float*)d_in[0];
  const float* w1 = (const float*)d_in[1];
  const float* v1 = (const float*)d_in[2];
  const float* w2 = (const float*)d_in[3];
  const int* eidx = (const int*)d_in[4];

  char* ws = (char*)d_ws;
  unsigned short* Xb  = (unsigned short*)(ws);                  // 16 MiB
  unsigned short* W1b = (unsigned short*)(ws + (16l << 20));    // 32 MiB
  unsigned short* V1b = (unsigned short*)(ws + (48l << 20));    // 32 MiB
  unsigned short* W2T = (unsigned short*)(ws + (80l << 20));    // 32 MiB
  unsigned short* Hb  = (unsigned short*)(ws + (112l << 20));   // 64 MiB
  float* out = (float*)d_out;

  long slab = (long)FFN_DIM * D_DIM;
  convert_kernel<<<2048, 256, 0, stream>>>(x,  eidx, 0,    Xb,  (long)T_DIM * D_DIM);
  convert_kernel<<<2048, 256, 0, stream>>>(w1, eidx, slab, W1b, slab);
  convert_kernel<<<2048, 256, 0, stream>>>(v1, eidx, slab, V1b, slab);
  transpose_kernel<<<dim3(D_DIM / 32, FFN_DIM / 32), 256, 0, stream>>>(w2, eidx, W2T);
  gemm1_silu<<<dim3(FFN_DIM / 64, T_DIM / 128), 256, 0, stream>>>(Xb, W1b, V1b, Hb);
  gemm2<<<dim3(D_DIM / 128, T_DIM / 128), 256, 0, stream>>>(Hb, W2T, out);
}

// Round 2
// 502.446 us; speedup vs baseline: 1.1256x; 1.1256x over previous
//
#include <hip/hip_runtime.h>

#define E_NUM 8
#define FFN_DIM 8192
#define D_DIM 2048
#define T_DIM 4096

using bf16x8 = __attribute__((ext_vector_type(8))) short;
using f32x4  = __attribute__((ext_vector_type(4))) float;
using u16x8  = __attribute__((ext_vector_type(8))) unsigned short;

__device__ __forceinline__ unsigned short f2bf(float f) {
  union { float f; unsigned int u; } v; v.f = f;
  unsigned int u = v.u;
  unsigned int r = (u + 0x7FFFu + ((u >> 16) & 1u)) >> 16;
  return (unsigned short)r;
}

__device__ __forceinline__ void gload16(const unsigned short* g, const unsigned short* l) {
  __builtin_amdgcn_global_load_lds(
      (const __attribute__((address_space(1))) void*)g,
      (__attribute__((address_space(3))) void*)l, 16, 0, 0);
}

// ---------- prep: fp32 -> bf16 convert (optionally slab-offset by *eidx) ----------
__global__ void convert_kernel(const float* __restrict__ src_base,
                               const int* __restrict__ eidx, long slab,
                               unsigned short* __restrict__ dst, long n) {
  const float* src = src_base + (long)(*eidx) * slab;
  long stride = (long)gridDim.x * blockDim.x;
  for (long i = (long)blockIdx.x * blockDim.x + threadIdx.x; i * 8 < n; i += stride) {
    long e = i * 8;
    const float4* p = (const float4*)(src + e);
    float4 f0 = p[0], f1 = p[1];
    u16x8 o;
    o[0] = f2bf(f0.x); o[1] = f2bf(f0.y); o[2] = f2bf(f0.z); o[3] = f2bf(f0.w);
    o[4] = f2bf(f1.x); o[5] = f2bf(f1.y); o[6] = f2bf(f1.z); o[7] = f2bf(f1.w);
    *(u16x8*)(dst + e) = o;
  }
}

// ---------- prep: transpose w2 slab (FFN,D) fp32 -> (D,FFN) bf16 ----------
__global__ void transpose_kernel(const float* __restrict__ w2,
                                 const int* __restrict__ eidx,
                                 unsigned short* __restrict__ dst) {
  __shared__ unsigned short tile[32][33];
  const float* src = w2 + (long)(*eidx) * (long)FFN_DIM * D_DIM;
  int d0 = blockIdx.x << 5;
  int f0 = blockIdx.y << 5;
  int tx = threadIdx.x & 31, ty = threadIdx.x >> 5;
#pragma unroll
  for (int i = 0; i < 4; ++i) {
    int f = ty + i * 8;
    tile[f][tx] = f2bf(src[(long)(f0 + f) * D_DIM + d0 + tx]);
  }
  __syncthreads();
#pragma unroll
  for (int i = 0; i < 4; ++i) {
    int d = ty + i * 8;
    dst[(long)(d0 + d) * FFN_DIM + f0 + tx] = tile[tx][d];
  }
}

// ---------- GEMM1 fused, 4-phase counted-vmcnt schedule ----------
// tile 256(m) x 128(n), BK=64, 8 waves (4M x 2N), per-wave 64x64 dual output.
// LDS: A 2x(256x64), B1 2x(128x64), B2 2x(128x64) bf16 = 128 KiB.
// Per K-tile: 8 staging rounds (A:0-3, B1:4-5, B2:6-7), 2 gload/phase,
// vmcnt(2) only twice per tile (end P0: rounds 6-7 ready; end P3: next rounds 0-5 ready).
// LDS swizzle: slot' = slot ^ (row&7) (linear gload dest, pre-swizzled global src, XOR'd read).
__global__ __launch_bounds__(512, 2) void gemm1_silu(
    const unsigned short* __restrict__ Xb,    // (4096,2048)
    const unsigned short* __restrict__ W1b,   // (8192,2048)
    const unsigned short* __restrict__ V1b,   // (8192,2048)
    unsigned short* __restrict__ Hb) {        // (4096,8192)
  __shared__ __align__(16) unsigned short sA[2 * 256 * 64];
  __shared__ __align__(16) unsigned short sB1[2 * 128 * 64];
  __shared__ __align__(16) unsigned short sB2[2 * 128 * 64];

  const int tid = threadIdx.x;
  const int wv = tid >> 6, l = tid & 63;
  const int wm = wv >> 1, wn = wv & 1;           // 4M x 2N waves
  const int kq = l >> 4, lr = l & 15;
  const int m0 = blockIdx.y << 8;                // *256
  const int n0 = blockIdx.x << 7;                // *128

  // staging: thread covers row (round*64 + tid/8), 16B slot position tid&7,
  // which must hold global slot (tid&7) ^ (row&7); row&7 == (tid>>3)&7.
  const int rsub = tid >> 3;
  const int sslot8 = ((tid & 7) ^ ((tid >> 3) & 7)) << 3;
  const unsigned short* gA0  = Xb  + (long)(m0 + rsub) * D_DIM + sslot8;
  const unsigned short* gB1r = W1b + (long)(n0 + rsub) * D_DIM + sslot8;
  const unsigned short* gB2r = V1b + (long)(n0 + rsub) * D_DIM + sslot8;

#define ST_A(r_)  gload16(gA0  + (long)((r_) * 64) * D_DIM + tc, sA  + sb * 16384 + (r_) * 4096 + wv * 512)
#define ST_B1(r_) gload16(gB1r + (long)((r_) * 64) * D_DIM + tc, sB1 + sb * 8192  + (r_) * 4096 + wv * 512)
#define ST_B2(r_) gload16(gB2r + (long)((r_) * 64) * D_DIM + tc, sB2 + sb * 8192  + (r_) * 4096 + wv * 512)
#define VMCNT2 asm volatile("s_waitcnt vmcnt(2)" ::: "memory")
#define VMCNT0 asm volatile("s_waitcnt vmcnt(0)" ::: "memory")
#define BAR __builtin_amdgcn_s_barrier()

  // fragment read offsets (elements), ks=0; ks=1 = off ^ 32 (toggles slot bit2)
  int raoff[4], rboff[4];
#pragma unroll
  for (int m = 0; m < 4; ++m) {
    int row = wm * 64 + m * 16 + lr;
    raoff[m] = row * 64 + ((kq ^ (row & 7)) << 3);
  }
#pragma unroll
  for (int n = 0; n < 4; ++n) {
    int row = wn * 64 + n * 16 + lr;
    rboff[n] = row * 64 + ((kq ^ (row & 7)) << 3);
  }

  f32x4 acc1[4][4], acc2[4][4];
  f32x4 z = {0.f, 0.f, 0.f, 0.f};
#pragma unroll
  for (int m = 0; m < 4; ++m)
#pragma unroll
    for (int n = 0; n < 4; ++n) { acc1[m][n] = z; acc2[m][n] = z; }

  // prologue: stage tile 0, wait rounds 0-5 (2 outstanding = rounds 6,7)
  {
    int tc = 0, sb = 0;
    ST_A(0); ST_A(1); ST_A(2); ST_A(3);
    ST_B1(0); ST_B1(1); ST_B2(0); ST_B2(1);
    VMCNT2;
    BAR;
  }

  const int NT = D_DIM / 64;  // 32
  for (int t = 0; t < NT; ++t) {
    const int db = t & 1;
    const unsigned short* Ab  = sA  + db * 16384;
    const unsigned short* B1b = sB1 + db * 8192;
    const unsigned short* B2b = sB2 + db * 8192;
    const int pf = (t < NT - 1);
    const int tc = (t + 1) << 6;
    const int sb = db ^ 1;
    bf16x8 af[4], bf_[4];

    // ---- P0: A k0 + B1 k0 frags; stage next A0,A1; MFMA acc1 k0 ----
#pragma unroll
    for (int m = 0; m < 4; ++m) af[m] = *(const bf16x8*)(Ab + raoff[m]);
#pragma unroll
    for (int n = 0; n < 4; ++n) bf_[n] = *(const bf16x8*)(B1b + rboff[n]);
    if (pf) { ST_A(0); ST_A(1); }
    BAR;
    __builtin_amdgcn_s_setprio(1);
#pragma unroll
    for (int m = 0; m < 4; ++m)
#pragma unroll
      for (int n = 0; n < 4; ++n)
        acc1[m][n] = __builtin_amdgcn_mfma_f32_16x16x32_bf16(af[m], bf_[n], acc1[m][n], 0, 0, 0);
    __builtin_amdgcn_s_setprio(0);
    if (pf) { VMCNT2; } else { VMCNT0; }   // rounds 6-7 of t landed
    BAR;

    // ---- P1: B2 k0 frags; stage next A2,A3; MFMA acc2 k0 ----
#pragma unroll
    for (int n = 0; n < 4; ++n) bf_[n] = *(const bf16x8*)(B2b + rboff[n]);
    if (pf) { ST_A(2); ST_A(3); }
    BAR;
    __builtin_amdgcn_s_setprio(1);
#pragma unroll
    for (int m = 0; m < 4; ++m)
#pragma unroll
      for (int n = 0; n < 4; ++n)
        acc2[m][n] = __builtin_amdgcn_mfma_f32_16x16x32_bf16(af[m], bf_[n], acc2[m][n], 0, 0, 0);
    __builtin_amdgcn_s_setprio(0);
    BAR;

    // ---- P2: A k1 + B1 k1 frags; stage next B1; MFMA acc1 k1 ----
#pragma unroll
    for (int m = 0; m < 4; ++m) af[m] = *(const bf16x8*)(Ab + (raoff[m] ^ 32));
#pragma unroll
    for (int n = 0; n < 4; ++n) bf_[n] = *(const bf16x8*)(B1b + (rboff[n] ^ 32));
    if (pf) { ST_B1(0); ST_B1(1); }
    BAR;
    __builtin_amdgcn_s_setprio(1);
#pragma unroll
    for (int m = 0; m < 4; ++m)
#pragma unroll
      for (int n = 0; n < 4; ++n)
        acc1[m][n] = __builtin_amdgcn_mfma_f32_16x16x32_bf16(af[m], bf_[n], acc1[m][n], 0, 0, 0);
    __builtin_amdgcn_s_setprio(0);
    BAR;

    // ---- P3: B2 k1 frags; stage next B2; MFMA acc2 k1 ----
#pragma unroll
    for (int n = 0; n < 4; ++n) bf_[n] = *(const bf16x8*)(B2b + (rboff[n] ^ 32));
    if (pf) { ST_B2(0); ST_B2(1); }
    BAR;
    __builtin_amdgcn_s_setprio(1);
#pragma unroll
    for (int m = 0; m < 4; ++m)
#pragma unroll
      for (int n = 0; n < 4; ++n)
        acc2[m][n] = __builtin_amdgcn_mfma_f32_16x16x32_bf16(af[m], bf_[n], acc2[m][n], 0, 0, 0);
    __builtin_amdgcn_s_setprio(0);
    if (pf) { VMCNT2; }                    // next tile rounds 0-5 landed
    BAR;
  }

  // epilogue: h = silu(x1)*x2, bf16
#pragma unroll
  for (int m = 0; m < 4; ++m)
#pragma unroll
    for (int n = 0; n < 4; ++n)
#pragma unroll
      for (int r = 0; r < 4; ++r) {
        int row = m0 + wm * 64 + m * 16 + kq * 4 + r;
        int col = n0 + wn * 64 + n * 16 + lr;
        float x1 = acc1[m][n][r], x2 = acc2[m][n][r];
        float hv = x1 / (1.f + __expf(-x1)) * x2;
        Hb[(long)row * FFN_DIM + col] = f2bf(hv);
      }
#undef ST_A
#undef ST_B1
#undef ST_B2
}

// ---------- GEMM2: out = h @ w2  (A=(4096,8192) bf16, Bt=(2048,8192) bf16, out fp32) ----------
__global__ __launch_bounds__(256) void gemm2(
    const unsigned short* __restrict__ Hb,
    const unsigned short* __restrict__ W2T,
    float* __restrict__ out) {
  __shared__ __align__(16) unsigned short sA[128 * 32];
  __shared__ __align__(16) unsigned short sB[128 * 32];

  const int tid = threadIdx.x;
  const int w = tid >> 6, l = tid & 63;
  const int m0 = blockIdx.y << 7;
  const int n0 = blockIdx.x << 7;
  const int wm = w >> 1, wn = w & 1;
  const int kq = l >> 4, lr = l & 15;

  f32x4 z = {0.f, 0.f, 0.f, 0.f};
  f32x4 acc[4][4];
#pragma unroll
  for (int m = 0; m < 4; ++m)
#pragma unroll
    for (int n = 0; n < 4; ++n) acc[m][n] = z;

  const int colg = (l & 3) * 8;
  const int rsub = l >> 2;
  const unsigned short* gA0 = Hb + (long)(m0 + (w * 2 + 0) * 16 + rsub) * FFN_DIM + colg;
  const unsigned short* gA1 = Hb + (long)(m0 + (w * 2 + 1) * 16 + rsub) * FFN_DIM + colg;
  const unsigned short* gB0 = W2T + (long)(n0 + (w * 2 + 0) * 16 + rsub) * FFN_DIM + colg;
  const unsigned short* gB1 = W2T + (long)(n0 + (w * 2 + 1) * 16 + rsub) * FFN_DIM + colg;
  unsigned short* lA0 = sA + (w * 2 + 0) * 512;
  unsigned short* lA1 = sA + (w * 2 + 1) * 512;
  unsigned short* lB0 = sB + (w * 2 + 0) * 512;
  unsigned short* lB1 = sB + (w * 2 + 1) * 512;

  for (int k0 = 0; k0 < FFN_DIM; k0 += 32) {
    if (k0) __syncthreads();
    gload16(gA0 + k0, lA0);
    gload16(gA1 + k0, lA1);
    gload16(gB0 + k0, lB0);
    gload16(gB1 + k0, lB1);
    __syncthreads();

    const bf16x8* pA = (const bf16x8*)sA;
    const bf16x8* pB = (const bf16x8*)sB;
    bf16x8 a[4], b[4];
#pragma unroll
    for (int m = 0; m < 4; ++m) a[m] = pA[(wm * 64 + m * 16 + lr) * 4 + kq];
#pragma unroll
    for (int n = 0; n < 4; ++n) b[n] = pB[(wn * 64 + n * 16 + lr) * 4 + kq];
#pragma unroll
    for (int m = 0; m < 4; ++m)
#pragma unroll
      for (int n = 0; n < 4; ++n)
        acc[m][n] = __builtin_amdgcn_mfma_f32_16x16x32_bf16(a[m], b[n], acc[m][n], 0, 0, 0);
  }

#pragma unroll
  for (int m = 0; m < 4; ++m)
#pragma unroll
    for (int n = 0; n < 4; ++n)
#pragma unroll
      for (int r = 0; r < 4; ++r) {
        int row = m0 + wm * 64 + m * 16 + kq * 4 + r;
        int col = n0 + wn * 64 + n * 16 + lr;
        out[(long)row * D_DIM + col] = acc[m][n][r];
      }
}

extern "C" void kernel_launch(void* const* d_in, const int* in_sizes, int n_in,
                              void* d_out, int out_size, void* d_ws, size_t ws_size,
                              hipStream_t stream) {
  const float* x  = (const float*)d_in[0];
  const float* w1 = (const float*)d_in[1];
  const float* v1 = (const float*)d_in[2];
  const float* w2 = (const float*)d_in[3];
  const int* eidx = (const int*)d_in[4];

  char* ws = (char*)d_ws;
  unsigned short* Xb  = (unsigned short*)(ws);                  // 16 MiB
  unsigned short* W1b = (unsigned short*)(ws + (16l << 20));    // 32 MiB
  unsigned short* V1b = (unsigned short*)(ws + (48l << 20));    // 32 MiB
  unsigned short* W2T = (unsigned short*)(ws + (80l << 20));    // 32 MiB
  unsigned short* Hb  = (unsigned short*)(ws + (112l << 20));   // 64 MiB
  float* out = (float*)d_out;

  long slab = (long)FFN_DIM * D_DIM;
  convert_kernel<<<2048, 256, 0, stream>>>(x,  eidx, 0,    Xb,  (long)T_DIM * D_DIM);
  convert_kernel<<<2048, 256, 0, stream>>>(w1, eidx, slab, W1b, slab);
  convert_kernel<<<2048, 256, 0, stream>>>(v1, eidx, slab, V1b, slab);
  transpose_kernel<<<dim3(D_DIM / 32, FFN_DIM / 32), 256, 0, stream>>>(w2, eidx, W2T);
  gemm1_silu<<<dim3(FFN_DIM / 128, T_DIM / 256), 512, 0, stream>>>(Xb, W1b, V1b, Hb);
  gemm2<<<dim3(D_DIM / 128, T_DIM / 128), 256, 0, stream>>>(Hb, W2T, out);
}